// Round 17
// baseline (529.520 us; speedup 1.0000x reference)
//
#include <hip/hip_runtime.h>
#include <hip/hip_bf16.h>

#define N 8192
#define HID 64
#define NJC 16   // j-chunks (512 cols each); grid = 16 jc x 16 ig = 256 blocks

typedef __attribute__((ext_vector_type(4))) float f32x4;
typedef __attribute__((ext_vector_type(8))) __bf16 bf16x8;

// raw v_exp_f32 (2^x): args bounded (|x| <= ~2.3) -> exact; avoids OCML path.
#if __has_builtin(__builtin_amdgcn_exp2f)
__device__ __forceinline__ float fast_exp2(float x) {
  return __builtin_amdgcn_exp2f(x);
}
#else
__device__ __forceinline__ float fast_exp2(float x) {
  float r;
  asm volatile("v_exp_f32 %0, %1" : "=v"(r) : "v"(x));
  return r;
}
#endif

__device__ __forceinline__ f32x4 nt_load4(const float* p) {
  return __builtin_nontemporal_load((const f32x4*)p);
}

// async global->LDS, 16B per lane, dest = wave-uniform base + lane*16
__device__ __forceinline__ void gload_lds16(const void* g, float* l) {
  __builtin_amdgcn_global_load_lds(
      (const __attribute__((address_space(1))) void*)g,
      (__attribute__((address_space(3))) void*)l, 16, 0, 0);
}

// ---------------- Kernel A: projection + L2 normalize -> bf16 ----------------
__global__ __launch_bounds__(256) void proj_kernel(
    const float* __restrict__ x1, const float* __restrict__ x2,
    const float* __restrict__ W1, const float* __restrict__ b1,
    const float* __restrict__ W2, const float* __restrict__ b2,
    __bf16* __restrict__ Z1h, __bf16* __restrict__ Z2h)
{
  __shared__ __align__(16) float w1s[64*68];
  __shared__ __align__(16) float w2s[64*68];
  __shared__ __align__(16) float xs[4][64];
  __shared__ __align__(16) float hs[4][64];

  const int tid  = threadIdx.x;
  const int lane = tid & 63;
  const int w    = tid >> 6;

  for (int idx = tid; idx < 64*64; idx += 256) {
    int j = idx >> 6, k = idx & 63;
    w1s[j*68+k] = W1[idx];
    w2s[j*68+k] = W2[idx];
  }
  __syncthreads();

  const float bias1 = b1[lane];
  const float bias2 = b2[lane];

  const int wave_global = blockIdx.x * 4 + w;   // 0..4095 with grid=1024
  #pragma unroll 1
  for (int it = 0; it < 4; ++it) {
    int R = wave_global * 4 + it;               // 0..16383
    const float* src; __bf16* dst;
    if (R < N) { src = x1 + (size_t)R*HID;      dst = Z1h + (size_t)R*HID; }
    else       { src = x2 + (size_t)(R-N)*HID;  dst = Z2h + (size_t)(R-N)*HID; }

    float xv = src[lane];
    xs[w][lane] = xv;
    float acc = bias1;
    #pragma unroll
    for (int qq = 0; qq < 16; ++qq) {
      f32x4 xq = *(const f32x4*)&xs[w][qq*4];
      f32x4 wq = *(const f32x4*)&w1s[lane*68 + qq*4];
      acc += xq.x*wq.x + xq.y*wq.y + xq.z*wq.z + xq.w*wq.w;
    }
    float h = acc > 0.f ? acc : expm1f(acc);             // ELU (alpha=1)
    hs[w][lane] = h;
    float acc2 = bias2;
    #pragma unroll
    for (int qq = 0; qq < 16; ++qq) {
      f32x4 hq = *(const f32x4*)&hs[w][qq*4];
      f32x4 wq = *(const f32x4*)&w2s[lane*68 + qq*4];
      acc2 += hq.x*wq.x + hq.y*wq.y + hq.z*wq.z + hq.w*wq.w;
    }
    float z = acc2;
    float ss = z*z;
    #pragma unroll
    for (int m = 1; m < 64; m <<= 1) ss += __shfl_xor(ss, m);
    float inv = 1.0f / fmaxf(sqrtf(ss), 1e-12f);
    dst[lane] = (__bf16)(z * inv);
  }
}

// ---------------- Kernel B: exp-sim, 512x512 tile (min-HBM-bytes) -----------
// Calibration (R8/R14/R15/R16): sim_dur ≈ FETCH / ~3.4 TB/s; Z-request bytes
// = 64M x 256 x (1/I + 1/J). R14's (I=512,J=128) -> 168 MB excess (matches
// counters). This round: (I=512, J=512), grid 256 (16 jc x 16 ig), 512-thread
// blocks, 128 KB LDS (512 j-rows of Z1+Z2 staged ONCE, one barrier total)
// -> Z-requests 67 MB. pos per-row segments grow 512B -> 2KB contiguous.
// Same-jc blocks land on one XCD (b%8 == jc%8) -> staged-Z L2 reuse.
// Per wave: 4 strips of 16 i-rows (i-frags once, registers); per strip 4
// groups of 8 COMPC with 2-bank pos prefetch (PA/PB, static names, one group
// ahead). Data path byte-identical to absmax-0 R14-R16 code.
__global__ __launch_bounds__(512, 2) void sim_kernel(
    const __bf16* __restrict__ Z1h, const __bf16* __restrict__ Z2h,
    const float* __restrict__ pos,
    float* __restrict__ pr1, float* __restrict__ pn1,
    float* __restrict__ pr2, float* __restrict__ pn2)
{
  __shared__ __align__(16) float zs1[512*32];   // 64 KB: Z1 rows jb..jb+511
  __shared__ __align__(16) float zs2[512*32];   // 64 KB: Z2 rows jb..jb+511

  const int tid  = threadIdx.x;
  const int lane = tid & 63;
  const int w    = tid >> 6;                    // 0..7
  const int r16  = lane & 15;
  const int q    = lane >> 4;

  const int jcid = blockIdx.x & 15;             // j-chunk id (16 chunks of 512)
  const int jb   = jcid * 512;
  const int ig   = (blockIdx.x >> 4) * 512;     // i-group base (16 groups)

  // ---- stage the j-chunk once: content slot s of row R stored at slot
  // s^(R&7) (involution on the GLOBAL source; linear LDS dest). 16 insts/wave.
  {
    const int r8 = lane >> 3;                   // 8 rows per inst
    const int sl = (lane & 7) ^ r8;             // swizzled source col-slot
    #pragma unroll
    for (int b = 0; b < 8; ++b) {
      const int row0 = w*64 + b*8;              // wave w stages rows w*64..+63
      gload_lds16(Z1h + (size_t)(jb + row0 + r8)*HID + sl*8, &zs1[row0*32]);
      gload_lds16(Z2h + (size_t)(jb + row0 + r8)*HID + sl*8, &zs2[row0*32]);
    }
  }
  __syncthreads();    // the ONLY barrier (drains the staging loads)

  const float Cexp = 1.8033688011112042f;       // 1/(TAU*ln2), TAU=0.8

  // one 16x16 j-subtile: swizzled LDS reads + dual MFMA + exp + gated acc
#define COMPC(S, PV) { \
    const int R  = (S)*16 + r16; \
    const int sw = r16 & 7; \
    bf16x8 b2lo = *(const bf16x8*)&zs2[R*32 + ((q    ) ^ sw)*4]; \
    bf16x8 b2hi = *(const bf16x8*)&zs2[R*32 + ((q + 4) ^ sw)*4]; \
    bf16x8 b1lo = *(const bf16x8*)&zs1[R*32 + ((q    ) ^ sw)*4]; \
    bf16x8 b1hi = *(const bf16x8*)&zs1[R*32 + ((q + 4) ^ sw)*4]; \
    f32x4 zero4 = {0.f,0.f,0.f,0.f}; \
    f32x4 d1 = __builtin_amdgcn_mfma_f32_16x16x32_bf16(b2lo, a1lo, zero4, 0,0,0); \
    d1       = __builtin_amdgcn_mfma_f32_16x16x32_bf16(b2hi, a1hi, d1,    0,0,0); \
    f32x4 d2 = __builtin_amdgcn_mfma_f32_16x16x32_bf16(b1lo, a2lo, zero4, 0,0,0); \
    d2       = __builtin_amdgcn_mfma_f32_16x16x32_bf16(b1hi, a2hi, d2,    0,0,0); \
    _Pragma("unroll") \
    for (int r = 0; r < 4; ++r) { \
      float e1 = fast_exp2(d1[r] * Cexp); \
      float e2 = fast_exp2(d2[r] * Cexp); \
      s1 += e1; n1 += e1 * PV[r]; \
      s2 += e2; n2 += e2 * PV[r]; \
    } }

  // load one 128-col group of pos quads (8 x NT f32x4, static bank names)
#define LOADP(P, G) { \
    const float* pg = prow + (G)*128; \
    P##0 = nt_load4(pg);       P##1 = nt_load4(pg + 16); \
    P##2 = nt_load4(pg + 32);  P##3 = nt_load4(pg + 48); \
    P##4 = nt_load4(pg + 64);  P##5 = nt_load4(pg + 80); \
    P##6 = nt_load4(pg + 96);  P##7 = nt_load4(pg + 112); \
  }

#define COMPG(G, P) { \
    COMPC((G)*8+0, P##0) COMPC((G)*8+1, P##1) COMPC((G)*8+2, P##2) \
    COMPC((G)*8+3, P##3) COMPC((G)*8+4, P##4) COMPC((G)*8+5, P##5) \
    COMPC((G)*8+6, P##6) COMPC((G)*8+7, P##7) }

  // 4 strips of 16 i-rows per wave
  #pragma unroll 1
  for (int st = 0; st < 4; ++st) {
    const int i0 = ig + w*64 + st*16;

    // i-frags once per strip (registers)
    const __bf16* z1r = Z1h + (size_t)(i0 + r16)*HID + q*8;
    const __bf16* z2r = Z2h + (size_t)(i0 + r16)*HID + q*8;
    const bf16x8 a1lo = *(const bf16x8*)(z1r);
    const bf16x8 a1hi = *(const bf16x8*)(z1r + 32);
    const bf16x8 a2lo = *(const bf16x8*)(z2r);
    const bf16x8 a2hi = *(const bf16x8*)(z2r + 32);

    const float* prow = pos + (size_t)(i0 + r16)*N + jb + q*4;
    f32x4 PA0,PA1,PA2,PA3,PA4,PA5,PA6,PA7;
    f32x4 PB0,PB1,PB2,PB3,PB4,PB5,PB6,PB7;

    float s1 = 0.f, n1 = 0.f, s2 = 0.f, n2 = 0.f;

    // 2-bank pos prefetch, one 128-col group ahead (static names)
    LOADP(PA, 0)
    LOADP(PB, 1)  COMPG(0, PA)
    LOADP(PA, 2)  COMPG(1, PB)
    LOADP(PB, 3)  COMPG(2, PA)
    COMPG(3, PB)

    // reduce j-partials across the 4 quads -> full sums per row i0+r16
    s1 += __shfl_xor(s1, 16); s1 += __shfl_xor(s1, 32);
    n1 += __shfl_xor(n1, 16); n1 += __shfl_xor(n1, 32);
    s2 += __shfl_xor(s2, 16); s2 += __shfl_xor(s2, 32);
    n2 += __shfl_xor(n2, 16); n2 += __shfl_xor(n2, 32);

    // unique writer per (jc,row): NT stores (64B contiguous per array)
    if (lane < 16) {
      const size_t pidx = (size_t)jcid*N + i0 + r16;
      __builtin_nontemporal_store(s1, &pr1[pidx]);
      __builtin_nontemporal_store(n1, &pn1[pidx]);
      __builtin_nontemporal_store(s2, &pr2[pidx]);
      __builtin_nontemporal_store(n2, &pn2[pidx]);
    }
  }
#undef COMPC
#undef LOADP
#undef COMPG
}

// ---------------- Kernel C: partial combine + loss reduction ----------------
// 32 blocks x 256 threads, one row per thread: sum the 16 j-chunk partials,
// row loss, block reduce, one atomicAdd per block (harness zeroes out).
__global__ __launch_bounds__(256) void loss_kernel(
    const float* __restrict__ pr1, const float* __restrict__ pn1,
    const float* __restrict__ pr2, const float* __restrict__ pn2,
    float* __restrict__ out)
{
  __shared__ float part[4];
  const int tid = threadIdx.x, lane = tid & 63, w = tid >> 6;
  const int row = blockIdx.x * 256 + tid;       // 8192 threads == N rows

  float rs1 = 0.f, nn1 = 0.f, rs2 = 0.f, nn2 = 0.f;
  #pragma unroll
  for (int jc = 0; jc < NJC; ++jc) {
    rs1 += pr1[(size_t)jc*N + row];
    nn1 += pn1[(size_t)jc*N + row];
    rs2 += pr2[(size_t)jc*N + row];
    nn2 += pn2[(size_t)jc*N + row];
  }
  float sc = -logf(nn1/(rs1 + 1e-8f) + 1e-8f);
  float mp = -logf(nn2/(rs2 + 1e-8f) + 1e-8f);
  float acc = (0.5f*sc + 0.5f*mp) * (1.0f/N);   // LAMBDA = 0.5

  #pragma unroll
  for (int m = 1; m < 64; m <<= 1) acc += __shfl_xor(acc, m);
  if (lane == 0) part[w] = acc;
  __syncthreads();
  if (tid == 0) atomicAdd(out, part[0] + part[1] + part[2] + part[3]);
}

extern "C" void kernel_launch(void* const* d_in, const int* in_sizes, int n_in,
                              void* d_out, int out_size, void* d_ws, size_t ws_size,
                              hipStream_t stream) {
  const float* x1  = (const float*)d_in[0];
  const float* x2  = (const float*)d_in[1];
  const float* W1  = (const float*)d_in[2];
  const float* b1  = (const float*)d_in[3];
  const float* W2  = (const float*)d_in[4];
  const float* b2  = (const float*)d_in[5];
  const float* pos = (const float*)d_in[6];

  char* ws = (char*)d_ws;
  __bf16* Z1h = (__bf16*)ws;
  __bf16* Z2h = (__bf16*)(ws + (size_t)N*HID*sizeof(__bf16));
  size_t zbytes = (size_t)2*N*HID*sizeof(__bf16);   // 2 MB
  float* pr1 = (float*)(ws + zbytes);               // NJC*N each (512 KB x4)
  float* pn1 = pr1 + (size_t)NJC*N;
  float* pr2 = pn1 + (size_t)NJC*N;
  float* pn2 = pr2 + (size_t)NJC*N;

  proj_kernel<<<1024, 256, 0, stream>>>(x1, x2, W1, b1, W2, b2, Z1h, Z2h);
  sim_kernel<<<256, 512, 0, stream>>>(Z1h, Z2h, pos, pr1, pn1, pr2, pn2);
  loss_kernel<<<32, 256, 0, stream>>>(pr1, pn1, pr2, pn2, (float*)d_out);
}

// Round 18
// 492.051 us; speedup vs baseline: 1.0761x; 1.0761x over previous
//
#include <hip/hip_runtime.h>
#include <hip/hip_bf16.h>

#define N 8192
#define HID 64
#define NJC 64   // j-chunks (128 cols each); sim grid = 64 jc x 16 ig = 1024

typedef __attribute__((ext_vector_type(4))) float f32x4;
typedef __attribute__((ext_vector_type(8))) __bf16 bf16x8;

// raw v_exp_f32 (2^x): args bounded (|x| <= ~2.3) -> exact; avoids OCML path.
#if __has_builtin(__builtin_amdgcn_exp2f)
__device__ __forceinline__ float fast_exp2(float x) {
  return __builtin_amdgcn_exp2f(x);
}
#else
__device__ __forceinline__ float fast_exp2(float x) {
  float r;
  asm volatile("v_exp_f32 %0, %1" : "=v"(r) : "v"(x));
  return r;
}
#endif

// async global->LDS, 16B per lane, dest = wave-uniform base + lane*16
__device__ __forceinline__ void gload_lds16(const void* g, float* l) {
  __builtin_amdgcn_global_load_lds(
      (const __attribute__((address_space(1))) void*)g,
      (__attribute__((address_space(3))) void*)l, 16, 0, 0);
}

// ---------------- Kernel M: pos (f32, binary) -> nibble byte-mask ----------
// 268MB -> 16MB at streaming BW (fully coalesced 1KB/wave-inst reads).
// byte[i] bit r = (pos[4i+r] != 0). R10-verified (absmax 0).
// This removes the 268MB stream from sim entirely: sim's FETCH collapses to
// ~mask(16MB)+Z(first-touch), and without the pos flush the 2MB Z working
// set stays L2-resident (R15/R16 counters showed the flush was re-fetching
// Z ~87x = the 170MB FETCH excess).
__global__ __launch_bounds__(256) void mask_kernel(
    const float* __restrict__ pos, unsigned char* __restrict__ mask)
{
  int idx = blockIdx.x * 256 + threadIdx.x;        // grid 2048 -> 0..524287
  const int stride = 2048 * 256;
  #pragma unroll 1
  for (int it = 0; it < 32; ++it) {                // 16,777,216 bytes total
    int i = idx + it * stride;
    f32x4 v = *(const f32x4*)(pos + (size_t)i * 4);
    unsigned b = (unsigned)(v.x != 0.f) | ((unsigned)(v.y != 0.f) << 1)
               | ((unsigned)(v.z != 0.f) << 2) | ((unsigned)(v.w != 0.f) << 3);
    mask[i] = (unsigned char)b;
  }
}

// ---------------- Kernel A: projection + L2 normalize -> bf16 ----------------
__global__ __launch_bounds__(256) void proj_kernel(
    const float* __restrict__ x1, const float* __restrict__ x2,
    const float* __restrict__ W1, const float* __restrict__ b1,
    const float* __restrict__ W2, const float* __restrict__ b2,
    __bf16* __restrict__ Z1h, __bf16* __restrict__ Z2h)
{
  __shared__ __align__(16) float w1s[64*68];
  __shared__ __align__(16) float w2s[64*68];
  __shared__ __align__(16) float xs[4][64];
  __shared__ __align__(16) float hs[4][64];

  const int tid  = threadIdx.x;
  const int lane = tid & 63;
  const int w    = tid >> 6;

  for (int idx = tid; idx < 64*64; idx += 256) {
    int j = idx >> 6, k = idx & 63;
    w1s[j*68+k] = W1[idx];
    w2s[j*68+k] = W2[idx];
  }
  __syncthreads();

  const float bias1 = b1[lane];
  const float bias2 = b2[lane];

  const int wave_global = blockIdx.x * 4 + w;   // 0..4095 with grid=1024
  #pragma unroll 1
  for (int it = 0; it < 4; ++it) {
    int R = wave_global * 4 + it;               // 0..16383
    const float* src; __bf16* dst;
    if (R < N) { src = x1 + (size_t)R*HID;      dst = Z1h + (size_t)R*HID; }
    else       { src = x2 + (size_t)(R-N)*HID;  dst = Z2h + (size_t)(R-N)*HID; }

    float xv = src[lane];
    xs[w][lane] = xv;
    float acc = bias1;
    #pragma unroll
    for (int qq = 0; qq < 16; ++qq) {
      f32x4 xq = *(const f32x4*)&xs[w][qq*4];
      f32x4 wq = *(const f32x4*)&w1s[lane*68 + qq*4];
      acc += xq.x*wq.x + xq.y*wq.y + xq.z*wq.z + xq.w*wq.w;
    }
    float h = acc > 0.f ? acc : expm1f(acc);             // ELU (alpha=1)
    hs[w][lane] = h;
    float acc2 = bias2;
    #pragma unroll
    for (int qq = 0; qq < 16; ++qq) {
      f32x4 hq = *(const f32x4*)&hs[w][qq*4];
      f32x4 wq = *(const f32x4*)&w2s[lane*68 + qq*4];
      acc2 += hq.x*wq.x + hq.y*wq.y + hq.z*wq.z + hq.w*wq.w;
    }
    float z = acc2;
    float ss = z*z;
    #pragma unroll
    for (int m = 1; m < 64; m <<= 1) ss += __shfl_xor(ss, m);
    float inv = 1.0f / fmaxf(sqrtf(ss), 1e-12f);
    dst[lane] = (__bf16)(z * inv);
  }
}

// ---------------- Kernel B: exp-sim, stage-once + byte-mask ----------------
// R14/R16 structure (I=512, J=128: j-chunk Z staged to LDS once, ONE barrier,
// barrier-free 8-iter i-sweep, unique-writer NT partial stores, 32KB LDS,
// 4 blocks/CU) with pos f32x4 quads -> R10-verified mask words:
// per 16-row x 128-col strip each lane loads TWO u32 (8B of mask) instead of
// 128B of pos floats; 8 __shfl route subtile words; bit (8q+r) gates n += e
// (bit-exact vs e*pv, pv in {0,1} — R10 absmax 0).
// Expected per calibrated law (dur ≈ FETCH/3.4TB/s): FETCH 440MB -> ~40MB.
__global__ __launch_bounds__(256, 4) void sim_kernel(
    const __bf16* __restrict__ Z1h, const __bf16* __restrict__ Z2h,
    const unsigned char* __restrict__ mask,
    float* __restrict__ pr1, float* __restrict__ pn1,
    float* __restrict__ pr2, float* __restrict__ pn2)
{
  __shared__ __align__(16) float zs1[128*32];   // 16 KB: Z1 rows jb..jb+127
  __shared__ __align__(16) float zs2[128*32];   // 16 KB: Z2 rows jb..jb+127

  const int tid  = threadIdx.x;
  const int lane = tid & 63;
  const int w    = tid >> 6;
  const int r16  = lane & 15;
  const int q    = lane >> 4;

  const int jcid = blockIdx.x & 63;             // j-chunk id (64 chunks of 128)
  const int jb   = jcid * 128;
  const int ig   = (blockIdx.x >> 6) * 512;     // i-group base (16 groups)

  // ---- stage the j-chunk once: content slot s of row R stored at slot
  // s^(R&7) (involution on the GLOBAL source; linear LDS dest) ----
  {
    const int r8 = lane >> 3;                   // 8 rows per inst
    const int sl = (lane & 7) ^ r8;             // swizzled source col-slot
    #pragma unroll
    for (int b = 0; b < 4; ++b) {
      const int row0 = w*32 + b*8;              // wave w stages rows w*32..+31
      gload_lds16(Z1h + (size_t)(jb + row0 + r8)*HID + sl*8, &zs1[row0*32]);
      gload_lds16(Z2h + (size_t)(jb + row0 + r8)*HID + sl*8, &zs2[row0*32]);
    }
  }
  __syncthreads();    // the ONLY barrier (drains the staging loads)

  const float Cexp = 1.8033688011112042f;       // 1/(TAU*ln2), TAU=0.8

  // one 16x16 j-subtile: swizzled LDS reads + dual MFMA + exp + gated acc
#define COMPC(S, MK) { \
    const int R  = (S)*16 + r16; \
    const int sw = r16 & 7; \
    bf16x8 b2lo = *(const bf16x8*)&zs2[R*32 + ((q    ) ^ sw)*4]; \
    bf16x8 b2hi = *(const bf16x8*)&zs2[R*32 + ((q + 4) ^ sw)*4]; \
    bf16x8 b1lo = *(const bf16x8*)&zs1[R*32 + ((q    ) ^ sw)*4]; \
    bf16x8 b1hi = *(const bf16x8*)&zs1[R*32 + ((q + 4) ^ sw)*4]; \
    f32x4 zero4 = {0.f,0.f,0.f,0.f}; \
    f32x4 d1 = __builtin_amdgcn_mfma_f32_16x16x32_bf16(b2lo, a1lo, zero4, 0,0,0); \
    d1       = __builtin_amdgcn_mfma_f32_16x16x32_bf16(b2hi, a1hi, d1,    0,0,0); \
    f32x4 d2 = __builtin_amdgcn_mfma_f32_16x16x32_bf16(b1lo, a2lo, zero4, 0,0,0); \
    d2       = __builtin_amdgcn_mfma_f32_16x16x32_bf16(b1hi, a2hi, d2,    0,0,0); \
    _Pragma("unroll") \
    for (int r = 0; r < 4; ++r) { \
      float e1 = fast_exp2(d1[r] * Cexp); \
      float e2 = fast_exp2(d2[r] * Cexp); \
      s1 += e1; s2 += e2; \
      if (((MK) >> (8*q + r)) & 1u) { n1 += e1; n2 += e2; } \
    } }

  #pragma unroll 1
  for (int it = 0; it < 8; ++it) {
    const int i0 = ig + it*64 + w*16;

    // i-frags (L2-resident now that the pos stream no longer flushes L2)
    const __bf16* z1r = Z1h + (size_t)(i0 + r16)*HID + q*8;
    const __bf16* z2r = Z2h + (size_t)(i0 + r16)*HID + q*8;
    const bf16x8 a1lo = *(const bf16x8*)(z1r);
    const bf16x8 a1hi = *(const bf16x8*)(z1r + 32);
    const bf16x8 a2lo = *(const bf16x8*)(z2r);
    const bf16x8 a2hi = *(const bf16x8*)(z2r + 32);

    // mask for this 16x128 strip: row i0+r16, bytes jcid*32 .. +32.
    // Lane (q,r16) loads words q and 4+q (u32 at byte offsets 4q, 16+4q).
    const unsigned char* mrow = mask + (size_t)(i0 + r16)*(N/4) + jcid*32;
    const unsigned W0 = *(const unsigned*)(mrow + 4*q);
    const unsigned W1 = *(const unsigned*)(mrow + 16 + 4*q);

    // route word S to all lanes: word S (S<4) lives in lane (S,r16)'s W0,
    // word S (S>=4) in lane (S-4,r16)'s W1.  (R10 pattern, absmax 0.)
    const unsigned M0 = __shfl((int)W0,      r16);
    const unsigned M1 = __shfl((int)W0, 16 + r16);
    const unsigned M2 = __shfl((int)W0, 32 + r16);
    const unsigned M3 = __shfl((int)W0, 48 + r16);
    const unsigned M4 = __shfl((int)W1,      r16);
    const unsigned M5 = __shfl((int)W1, 16 + r16);
    const unsigned M6 = __shfl((int)W1, 32 + r16);
    const unsigned M7 = __shfl((int)W1, 48 + r16);

    float s1 = 0.f, n1 = 0.f, s2 = 0.f, n2 = 0.f;

    COMPC(0, M0) COMPC(1, M1) COMPC(2, M2) COMPC(3, M3)
    COMPC(4, M4) COMPC(5, M5) COMPC(6, M6) COMPC(7, M7)

    // reduce j-partials across the 4 quads -> full sums per row i0+r16
    s1 += __shfl_xor(s1, 16); s1 += __shfl_xor(s1, 32);
    n1 += __shfl_xor(n1, 16); n1 += __shfl_xor(n1, 32);
    s2 += __shfl_xor(s2, 16); s2 += __shfl_xor(s2, 32);
    n2 += __shfl_xor(n2, 16); n2 += __shfl_xor(n2, 32);

    // unique writer per (jc,row): NT stores (64B contiguous per array)
    if (lane < 16) {
      const size_t pidx = (size_t)jcid*N + i0 + r16;
      __builtin_nontemporal_store(s1, &pr1[pidx]);
      __builtin_nontemporal_store(n1, &pn1[pidx]);
      __builtin_nontemporal_store(s2, &pr2[pidx]);
      __builtin_nontemporal_store(n2, &pn2[pidx]);
    }
  }
#undef COMPC
}

// ---------------- Kernel C: partial combine + loss reduction ----------------
// 32 blocks x 256 threads, one row per thread: sum the 64 j-chunk partials,
// row loss, block reduce, one atomicAdd per block (harness zeroes out).
__global__ __launch_bounds__(256) void loss_kernel(
    const float* __restrict__ pr1, const float* __restrict__ pn1,
    const float* __restrict__ pr2, const float* __restrict__ pn2,
    float* __restrict__ out)
{
  __shared__ float part[4];
  const int tid = threadIdx.x, lane = tid & 63, w = tid >> 6;
  const int row = blockIdx.x * 256 + tid;       // 8192 threads == N rows

  float rs1 = 0.f, nn1 = 0.f, rs2 = 0.f, nn2 = 0.f;
  #pragma unroll 4
  for (int jc = 0; jc < NJC; ++jc) {
    rs1 += pr1[(size_t)jc*N + row];
    nn1 += pn1[(size_t)jc*N + row];
    rs2 += pr2[(size_t)jc*N + row];
    nn2 += pn2[(size_t)jc*N + row];
  }
  float sc = -logf(nn1/(rs1 + 1e-8f) + 1e-8f);
  float mp = -logf(nn2/(rs2 + 1e-8f) + 1e-8f);
  float acc = (0.5f*sc + 0.5f*mp) * (1.0f/N);   // LAMBDA = 0.5

  #pragma unroll
  for (int m = 1; m < 64; m <<= 1) acc += __shfl_xor(acc, m);
  if (lane == 0) part[w] = acc;
  __syncthreads();
  if (tid == 0) atomicAdd(out, part[0] + part[1] + part[2] + part[3]);
}

extern "C" void kernel_launch(void* const* d_in, const int* in_sizes, int n_in,
                              void* d_out, int out_size, void* d_ws, size_t ws_size,
                              hipStream_t stream) {
  const float* x1  = (const float*)d_in[0];
  const float* x2  = (const float*)d_in[1];
  const float* W1  = (const float*)d_in[2];
  const float* b1  = (const float*)d_in[3];
  const float* W2  = (const float*)d_in[4];
  const float* b2  = (const float*)d_in[5];
  const float* pos = (const float*)d_in[6];

  char* ws = (char*)d_ws;
  __bf16* Z1h = (__bf16*)ws;
  __bf16* Z2h = (__bf16*)(ws + (size_t)N*HID*sizeof(__bf16));
  size_t zbytes = (size_t)2*N*HID*sizeof(__bf16);   // 2 MB
  float* pr1 = (float*)(ws + zbytes);               // NJC*N each (2 MB x4)
  float* pn1 = pr1 + (size_t)NJC*N;
  float* pr2 = pn1 + (size_t)NJC*N;
  float* pn2 = pr2 + (size_t)NJC*N;
  unsigned char* maskp = (unsigned char*)(pn2 + (size_t)NJC*N);  // 16 MB

  mask_kernel<<<2048, 256, 0, stream>>>(pos, maskp);
  proj_kernel<<<1024, 256, 0, stream>>>(x1, x2, W1, b1, W2, b2, Z1h, Z2h);
  sim_kernel<<<1024, 256, 0, stream>>>(Z1h, Z2h, maskp, pr1, pn1, pr2, pn2);
  loss_kernel<<<32, 256, 0, stream>>>(pr1, pn1, pr2, pn2, (float*)d_out);
}

// Round 20
// 397.752 us; speedup vs baseline: 1.3313x; 1.2371x over previous
//
#include <hip/hip_runtime.h>
#include <hip/hip_bf16.h>

#define N 8192
#define HID 64
#define JC 16   // J-chunks per I-tile: grid = 128*JC = 2048 blocks
                // 32KB LDS/block -> 5 blocks/CU resident (160/32), 20 waves/CU
                // (R13 had grid=1024 = exactly 4/CU; this is the +25% TLP lever)

typedef __attribute__((ext_vector_type(4))) float f32x4;
typedef __attribute__((ext_vector_type(8))) __bf16 bf16x8;

// raw v_exp_f32 (2^x): args bounded (|x| <= ~2.3) -> exact; avoids OCML path.
#if __has_builtin(__builtin_amdgcn_exp2f)
__device__ __forceinline__ float fast_exp2(float x) {
  return __builtin_amdgcn_exp2f(x);
}
#else
__device__ __forceinline__ float fast_exp2(float x) {
  float r;
  asm volatile("v_exp_f32 %0, %1" : "=v"(r) : "v"(x));
  return r;
}
#endif

// async global->LDS, 16B per lane, dest = wave-uniform base + lane*16
__device__ __forceinline__ void gload_lds16(const void* g, float* l) {
  __builtin_amdgcn_global_load_lds(
      (const __attribute__((address_space(1))) void*)g,
      (__attribute__((address_space(3))) void*)l, 16, 0, 0);
}

// ---------------- Kernel A: projection + L2 normalize -> bf16 ----------------
// h = elu(x @ W1^T + b1); z = h @ W2^T + b2; zhat = z / max(||z||, 1e-12)
// One wave per row-iteration; lane j = output feature j. W1/W2 in LDS with
// stride-68 padding. Also zero-inits the 4*N stat array (replaces memset).
__global__ __launch_bounds__(256) void proj_kernel(
    const float* __restrict__ x1, const float* __restrict__ x2,
    const float* __restrict__ W1, const float* __restrict__ b1,
    const float* __restrict__ W2, const float* __restrict__ b2,
    __bf16* __restrict__ Z1h, __bf16* __restrict__ Z2h,
    float* __restrict__ stats)
{
  __shared__ __align__(16) float w1s[64*68];
  __shared__ __align__(16) float w2s[64*68];
  __shared__ __align__(16) float xs[4][64];
  __shared__ __align__(16) float hs[4][64];

  const int tid  = threadIdx.x;
  const int lane = tid & 63;
  const int w    = tid >> 6;

  int gtid = blockIdx.x * 256 + tid;
  if (gtid < 4*N) stats[gtid] = 0.f;

  for (int idx = tid; idx < 64*64; idx += 256) {
    int j = idx >> 6, k = idx & 63;
    w1s[j*68+k] = W1[idx];
    w2s[j*68+k] = W2[idx];
  }
  __syncthreads();

  const float bias1 = b1[lane];
  const float bias2 = b2[lane];

  const int wave_global = blockIdx.x * 4 + w;   // 0..4095 with grid=1024
  #pragma unroll 1
  for (int it = 0; it < 4; ++it) {
    int R = wave_global * 4 + it;               // 0..16383
    const float* src; __bf16* dst;
    if (R < N) { src = x1 + (size_t)R*HID;      dst = Z1h + (size_t)R*HID; }
    else       { src = x2 + (size_t)(R-N)*HID;  dst = Z2h + (size_t)(R-N)*HID; }

    float xv = src[lane];
    xs[w][lane] = xv;
    float acc = bias1;
    #pragma unroll
    for (int qq = 0; qq < 16; ++qq) {
      f32x4 xq = *(const f32x4*)&xs[w][qq*4];
      f32x4 wq = *(const f32x4*)&w1s[lane*68 + qq*4];
      acc += xq.x*wq.x + xq.y*wq.y + xq.z*wq.z + xq.w*wq.w;
    }
    float h = acc > 0.f ? acc : expm1f(acc);             // ELU (alpha=1)
    hs[w][lane] = h;
    float acc2 = bias2;
    #pragma unroll
    for (int qq = 0; qq < 16; ++qq) {
      f32x4 hq = *(const f32x4*)&hs[w][qq*4];
      f32x4 wq = *(const f32x4*)&w2s[lane*68 + qq*4];
      acc2 += hq.x*wq.x + hq.y*wq.y + hq.z*wq.z + hq.w*wq.w;
    }
    float z = acc2;
    float ss = z*z;
    #pragma unroll
    for (int m = 1; m < 64; m <<= 1) ss += __shfl_xor(ss, m);
    float inv = 1.0f / fmaxf(sqrtf(ss), 1e-12f);
    dst[lane] = (__bf16)(z * inv);
  }
}

// ---------------- Kernel B: exp-sim (R13 skeleton, JC=16 occupancy bump) ----
// Verbatim the best-known R13 structure (total 415.8us, absmax 0): 2-phase
// global_load_lds double-buffer for Z (swizzled source, linear dest), pos
// f32x4 register banks issued one phase ahead, __syncthreads sync, fast_exp2.
// ONLY change: JC 8 -> 16 (grid 2048; j-chunk 512 cols = 8 steps/block),
// so 5 blocks/CU become resident (LDS 160/32) instead of exactly 4 -> +25%
// wave-level latency hiding on a latency-floored kernel.
__global__ __launch_bounds__(256, 4) void sim_kernel(
    const __bf16* __restrict__ Z1h, const __bf16* __restrict__ Z2h,
    const float* __restrict__ pos,
    float* __restrict__ rowsum1, float* __restrict__ num1,
    float* __restrict__ rowsum2, float* __restrict__ num2)
{
  __shared__ __align__(16) float zs1[2][2048];   // 64 rows x 128B, double buf
  __shared__ __align__(16) float zs2[2][2048];   // 32 KB total

  const int tid  = threadIdx.x;
  const int lane = tid & 63;
  const int w    = tid >> 6;
  const int r16  = lane & 15;
  const int q    = lane >> 4;

  const int bi  = blockIdx.x / JC;    // 0..127 I-tile
  const int jc  = blockIdx.x % JC;
  const int i0  = bi*64 + w*16;

  // i-side fragments: row i0+r16, k = q*8 (lo) / +32 (hi)
  const __bf16* z1r = Z1h + (size_t)(i0 + r16)*HID + q*8;
  const __bf16* z2r = Z2h + (size_t)(i0 + r16)*HID + q*8;
  const bf16x8 a1lo = *(const bf16x8*)(z1r);
  const bf16x8 a1hi = *(const bf16x8*)(z1r + 32);
  const bf16x8 a2lo = *(const bf16x8*)(z2r);
  const bf16x8 a2hi = *(const bf16x8*)(z2r + 32);

  float s1 = 0.f, n1 = 0.f, s2 = 0.f, n2 = 0.f;

  const int jbeg = jc * (N/JC);               // 512-col chunk, 8 x 64-col steps
  const float Cexp = 1.8033688011112042f;     // 1/(TAU*ln2), TAU=0.8
  const float* prow = pos + (size_t)(i0 + r16)*N + q*4;

  f32x4 PA0, PA1, PA2, PA3, PB0, PB1, PB2, PB3;   // pos banks, static names

#define STAGEZ(BUF, JJ) { \
    const int r8 = lane >> 3; \
    const int sl = (lane & 7) ^ r8; \
    gload_lds16(Z1h + (size_t)((JJ) + w*16     + r8)*HID + sl*8, &zs1[BUF][(w*16    )*32]); \
    gload_lds16(Z1h + (size_t)((JJ) + w*16 + 8 + r8)*HID + sl*8, &zs1[BUF][(w*16 + 8)*32]); \
    gload_lds16(Z2h + (size_t)((JJ) + w*16     + r8)*HID + sl*8, &zs2[BUF][(w*16    )*32]); \
    gload_lds16(Z2h + (size_t)((JJ) + w*16 + 8 + r8)*HID + sl*8, &zs2[BUF][(w*16 + 8)*32]); \
  }

#define LOADPOS(P, JJ) { \
    P##0 = *(const f32x4*)(prow + (JJ)); \
    P##1 = *(const f32x4*)(prow + (JJ) + 16); \
    P##2 = *(const f32x4*)(prow + (JJ) + 32); \
    P##3 = *(const f32x4*)(prow + (JJ) + 48); \
  }

#define COMPC(BUF, C, CC, PV) { \
    const int R  = (CC) + (C)*16 + r16; \
    const int sw = r16 & 7; \
    bf16x8 b2lo = *(const bf16x8*)&zs2[BUF][R*32 + ((q    ) ^ sw)*4]; \
    bf16x8 b2hi = *(const bf16x8*)&zs2[BUF][R*32 + ((q + 4) ^ sw)*4]; \
    bf16x8 b1lo = *(const bf16x8*)&zs1[BUF][R*32 + ((q    ) ^ sw)*4]; \
    bf16x8 b1hi = *(const bf16x8*)&zs1[BUF][R*32 + ((q + 4) ^ sw)*4]; \
    f32x4 zero4 = {0.f,0.f,0.f,0.f}; \
    f32x4 d1 = __builtin_amdgcn_mfma_f32_16x16x32_bf16(b2lo, a1lo, zero4, 0,0,0); \
    d1       = __builtin_amdgcn_mfma_f32_16x16x32_bf16(b2hi, a1hi, d1,    0,0,0); \
    f32x4 d2 = __builtin_amdgcn_mfma_f32_16x16x32_bf16(b1lo, a2lo, zero4, 0,0,0); \
    d2       = __builtin_amdgcn_mfma_f32_16x16x32_bf16(b1hi, a2hi, d2,    0,0,0); \
    _Pragma("unroll") \
    for (int r = 0; r < 4; ++r) { \
      float e1 = fast_exp2(d1[r] * Cexp); \
      float e2 = fast_exp2(d2[r] * Cexp); \
      s1 += e1; n1 += e1 * PV[r]; \
      s2 += e2; n2 += e2 * PV[r]; \
    } }

#define STEP(BUF, P) { COMPC(BUF,0,0,P##0) COMPC(BUF,1,0,P##1) COMPC(BUF,0,32,P##2) COMPC(BUF,1,32,P##3) }

  // prologue: tile 0 in flight
  STAGEZ(0, jbeg)
  LOADPOS(PA, jbeg)
  __syncthreads();                       // vmcnt(0): tile 0 + pos(0) landed

  #pragma unroll 1
  for (int tp = 0; tp < 3; ++tp) {       // steps t = 2*tp, 2*tp+1  (0..5)
    const int t0 = tp*2;
    STAGEZ(1, jbeg + (t0+1)*64)          // issue BEFORE compute: full phase to land
    LOADPOS(PB, jbeg + (t0+1)*64)
    STEP(0, PA)
    __syncthreads();
    STAGEZ(0, jbeg + (t0+2)*64)
    LOADPOS(PA, jbeg + (t0+2)*64)
    STEP(1, PB)
    __syncthreads();
  }
  // steps 6, 7
  STAGEZ(1, jbeg + 7*64)
  LOADPOS(PB, jbeg + 7*64)
  STEP(0, PA)
  __syncthreads();
  STEP(1, PB)

#undef STAGEZ
#undef LOADPOS
#undef COMPC
#undef STEP

  // reduce j-partials across the 4 quads -> full sums per row i0+r16
  s1 += __shfl_xor(s1, 16); s1 += __shfl_xor(s1, 32);
  n1 += __shfl_xor(n1, 16); n1 += __shfl_xor(n1, 32);
  s2 += __shfl_xor(s2, 16); s2 += __shfl_xor(s2, 32);
  n2 += __shfl_xor(n2, 16); n2 += __shfl_xor(n2, 32);

  if (lane < 16) {
    int row = i0 + r16;
    atomicAdd(&rowsum1[row], s1);
    atomicAdd(&num1[row],    n1);
    atomicAdd(&rowsum2[row], s2);
    atomicAdd(&num2[row],    n2);
  }
}

// ---------------- Kernel C: final loss reduction ----------------
__global__ __launch_bounds__(1024) void loss_kernel(
    const float* __restrict__ rowsum1, const float* __restrict__ num1,
    const float* __restrict__ rowsum2, const float* __restrict__ num2,
    float* __restrict__ out)
{
  __shared__ float part[16];
  const int tid = threadIdx.x, lane = tid & 63, w = tid >> 6;
  float acc = 0.f;
  for (int i = tid; i < N; i += 1024) {
    float sc = -logf(num1[i]/(rowsum1[i]+1e-8f) + 1e-8f);
    float mp = -logf(num2[i]/(rowsum2[i]+1e-8f) + 1e-8f);
    acc += 0.5f*sc + 0.5f*mp;   // LAMBDA = 0.5
  }
  #pragma unroll
  for (int m = 1; m < 64; m <<= 1) acc += __shfl_xor(acc, m);
  if (lane == 0) part[w] = acc;
  __syncthreads();
  if (tid == 0) {
    float t = 0.f;
    #pragma unroll
    for (int k = 0; k < 16; ++k) t += part[k];
    out[0] = t * (1.0f/N);
  }
}

extern "C" void kernel_launch(void* const* d_in, const int* in_sizes, int n_in,
                              void* d_out, int out_size, void* d_ws, size_t ws_size,
                              hipStream_t stream) {
  const float* x1  = (const float*)d_in[0];
  const float* x2  = (const float*)d_in[1];
  const float* W1  = (const float*)d_in[2];
  const float* b1  = (const float*)d_in[3];
  const float* W2  = (const float*)d_in[4];
  const float* b2  = (const float*)d_in[5];
  const float* pos = (const float*)d_in[6];

  char* ws = (char*)d_ws;
  __bf16* Z1h = (__bf16*)ws;
  __bf16* Z2h = (__bf16*)(ws + (size_t)N*HID*sizeof(__bf16));
  size_t zbytes = (size_t)2*N*HID*sizeof(__bf16);   // 2 MB
  float* rowsum1 = (float*)(ws + zbytes);
  float* num1    = rowsum1 + N;
  float* rowsum2 = num1 + N;
  float* num2    = rowsum2 + N;

  proj_kernel<<<1024, 256, 0, stream>>>(x1, x2, W1, b1, W2, b2, Z1h, Z2h, rowsum1);
  sim_kernel<<<128*JC, 256, 0, stream>>>(Z1h, Z2h, pos, rowsum1, num1, rowsum2, num2);
  loss_kernel<<<1, 1024, 0, stream>>>(rowsum1, num1, rowsum2, num2, (float*)d_out);
}